// Round 11
// baseline (121.109 us; speedup 1.0000x reference)
//
#include <hip/hip_runtime.h>

typedef short bf16x8 __attribute__((ext_vector_type(8)));
typedef short bf16x4 __attribute__((ext_vector_type(4)));
typedef float f32x4 __attribute__((ext_vector_type(4)));
typedef float f32x16 __attribute__((ext_vector_type(16)));
typedef int i32x4 __attribute__((ext_vector_type(4)));

#define DEVI static __device__ __forceinline__

// f32 -> bf16 round-to-nearest-even
DEVI unsigned short f2b(float f) {
  unsigned u = __float_as_uint(f);
  u += 0x7FFFu + ((u >> 16) & 1u);
  return (unsigned short)(u >> 16);
}

DEVI void gload16(const void* g, void* l) {
  __builtin_amdgcn_global_load_lds((const __attribute__((address_space(1))) void*)g,
                                   (__attribute__((address_space(3))) void*)l, 16, 0, 0);
}

// permlane32_swap: outa = {a.row0, b.row0}, outb = {a.row1, b.row1}
DEVI void pl32swap(int a, int b, int& outa, int& outb) {
#if __has_builtin(__builtin_amdgcn_permlane32_swap)
  auto r = __builtin_amdgcn_permlane32_swap(a, b, false, false);
  outa = ((const int*)&r)[0];
  outb = ((const int*)&r)[1];
#else
  int bp = __shfl_xor(b, 32);
  int ap = __shfl_xor(a, 32);
  outa = (threadIdx.x & 32) ? bp : a;
  outb = (threadIdx.x & 32) ? b : ap;
#endif
}

DEVI float halfmax(float x) {
  int o0, o1;
  pl32swap(__float_as_int(x), __float_as_int(x), o0, o1);
  return fmaxf(__int_as_float(o0), __int_as_float(o1));
}
DEVI float halfsum(float x) {
  int o0, o1;
  pl32swap(__float_as_int(x), __float_as_int(x), o0, o1);
  return __int_as_float(o0) + __int_as_float(o1);
}

// ------------------------------------------------------------------
// RoPE table: cst[s][j] = (cos, sin) packed float2, s<2048, j<32
// ------------------------------------------------------------------
__global__ void rope_table_kernel(float2* __restrict__ cst) {
  int i = blockIdx.x * 256 + threadIdx.x;     // 65536 total
  int s = i >> 5, j = i & 31;
  float inv = powf(10000.0f, -(float)j * (1.0f / 32.0f));
  float a = (float)s * inv;
  cst[i] = make_float2(cosf(a), sinf(a));
}

// ------------------------------------------------------------------
// x f32 -> bf16 (vectorized)
// ------------------------------------------------------------------
__global__ void cvt_x_kernel(const float* __restrict__ x, unsigned short* __restrict__ xb) {
  int i = blockIdx.x * 256 + threadIdx.x;     // n/4 threads
  float4 v = ((const float4*)x)[i];
  ushort4 o;
  o.x = f2b(v.x); o.y = f2b(v.y); o.z = f2b(v.z); o.w = f2b(v.w);
  ((ushort4*)xb)[i] = o;
}

// ------------------------------------------------------------------
// W [K][N] f32  ->  WT [N][K] bf16  (LDS 32x32 tile transpose)
// ------------------------------------------------------------------
__global__ void transpose_kernel(const float* __restrict__ W, unsigned short* __restrict__ WT,
                                 int K, int N) {
  __shared__ float tile[32][33];
  int n0 = blockIdx.x * 32, k0 = blockIdx.y * 32;
  int tx = threadIdx.x, ty = threadIdx.y;     // 32 x 8
#pragma unroll
  for (int i = 0; i < 32; i += 8)
    tile[ty + i][tx] = W[(size_t)(k0 + ty + i) * N + n0 + tx];
  __syncthreads();
#pragma unroll
  for (int i = 0; i < 32; i += 8)
    WT[(size_t)(n0 + ty + i) * K + k0 + tx] = f2b(tile[tx][ty + i]);
}

// ------------------------------------------------------------------
// Shared GEMM mainloop: 128x128 tile, 4 waves (2x2), rolling counted-vmcnt
// pipeline (same structure as gemm_out — est. 700-900 TF per sum constraint).
// ------------------------------------------------------------------
DEVI void gemm_mainloop(const unsigned short* __restrict__ A, const unsigned short* __restrict__ B,
                        unsigned short* As, unsigned short* Bs,   // each [2][8192]
                        int m0, int n0, int lane, int wid, int wr, int wc,
                        f32x4 acc[4][4]) {
  const int srow = lane >> 3;
  const int scc = ((lane & 7) ^ srow) * 8;
  const int rx = lane & 7;
  auto stage = [&](int k0, int nb) {
    unsigned short* Ad = As + nb * 8192;
    unsigned short* Bd = Bs + nb * 8192;
#pragma unroll
    for (int i = 0; i < 4; ++i) {
      const int c = i * 4 + wid;
      const int row = c * 8 + srow;
      gload16(A + (size_t)(m0 + row) * 1024 + k0 + scc, (char*)Ad + c * 1024);
      gload16(B + (size_t)(n0 + row) * 1024 + k0 + scc, (char*)Bd + c * 1024);
    }
  };
  auto compute = [&](int nb) {
    const unsigned short* Ab = As + nb * 8192;
    const unsigned short* Bb = Bs + nb * 8192;
#pragma unroll
    for (int kk = 0; kk < 64; kk += 32) {
      const int cc = (((kk >> 3) + (lane >> 4)) ^ rx) * 8;
      bf16x8 a[4], b[4];
#pragma unroll
      for (int mi = 0; mi < 4; ++mi)
        a[mi] = *(const bf16x8*)&Ab[(wr * 64 + mi * 16 + (lane & 15)) * 64 + cc];
#pragma unroll
      for (int ni = 0; ni < 4; ++ni)
        b[ni] = *(const bf16x8*)&Bb[(wc * 64 + ni * 16 + (lane & 15)) * 64 + cc];
      __builtin_amdgcn_s_setprio(1);
#pragma unroll
      for (int mi = 0; mi < 4; ++mi)
#pragma unroll
        for (int ni = 0; ni < 4; ++ni)
          acc[mi][ni] = __builtin_amdgcn_mfma_f32_16x16x32_bf16(a[mi], b[ni], acc[mi][ni], 0, 0, 0);
      __builtin_amdgcn_s_setprio(0);
    }
  };
  stage(0, 0);
  stage(64, 1);
  for (int t = 0; t < 15; ++t) {
    asm volatile("s_waitcnt vmcnt(8)" ::: "memory");
    __builtin_amdgcn_s_barrier();
    compute(t & 1);
    __builtin_amdgcn_s_barrier();
    if (t < 14) stage((t + 2) * 64, t & 1);
  }
  asm volatile("s_waitcnt vmcnt(0)" ::: "memory");
  __builtin_amdgcn_s_barrier();
  compute(1);
}

// ------------------------------------------------------------------
// GEMM1 v6: 128x128 tile, 4 waves, rolling counted-vmcnt mainloop (the
// gemm_out structure) + coalesced LDS-slab RoPE epilogue (from R9).
// grid (24,32)=768 blocks, 64KB LDS, 2 blocks/CU. Bijective XCD remap.
// ------------------------------------------------------------------
__global__ __launch_bounds__(256, 2) void gemm_qkv_kernel(
    const unsigned short* __restrict__ Xb, const unsigned short* __restrict__ WT,
    const float2* __restrict__ cst,
    unsigned short* __restrict__ Qb, unsigned short* __restrict__ Kb,
    unsigned short* __restrict__ VTb) {
  __shared__ unsigned short As[2][8192];      // 32 KB
  __shared__ unsigned short Bs[2][8192];      // 32 KB
  const int lane = threadIdx.x & 63, wid = threadIdx.x >> 6;
  // bijective XCD remap for 768 blocks: chunk of 96 per XCD
  const int flat = blockIdx.y * 24 + blockIdx.x;
  const int nf = (flat & 7) * 96 + (flat >> 3);
  const int bx = nf % 24, by = nf / 24;
  const int m0 = by * 128, n0 = bx * 128;
  const int wr = wid >> 1, wc = wid & 1;
  f32x4 acc[4][4] = {};
  gemm_mainloop(Xb, WT, &As[0][0], &Bs[0][0], m0, n0, lane, wid, wr, wc, acc);

  // ---- coalesced epilogue via wave-private LDS slab (64x72 ushort) ----
  __syncthreads();                            // all waves done with As/Bs
  unsigned short* slab = (unsigned short*)((char*)&As[0][0] + wid * 9216);
  const int n_base = n0 + wc * 64;            // one head chunk per wave
  const int ty = n_base >> 10;                // 0=q 1=k 2=v
  const int h = (n_base & 1023) >> 6;
  const int qrow = (lane >> 4) << 2;
  const int l15 = lane & 15;
  const int rlane = lane >> 3, clane = lane & 7;
  const int rowg = m0 + wr * 64;
  const int s_half = rowg & 2047, bb = rowg >> 11;

  if (ty < 2) {
    unsigned short* dst = (ty == 0) ? Qb : Kb;
#pragma unroll
    for (int mi = 0; mi < 4; ++mi) {
      const int rl0 = mi * 16 + qrow;
#pragma unroll
      for (int r = 0; r < 4; ++r) {
#pragma unroll
        for (int ni = 0; ni < 2; ++ni) {
          const int j = ni * 16 + l15;
          const float2 cs = cst[(s_half + rl0 + r) * 32 + j];
          const float x1 = acc[mi][ni][r], x2 = acc[mi][ni + 2][r];
          slab[(rl0 + r) * 72 + j]      = f2b(x1 * cs.x + x2 * cs.y);
          slab[(rl0 + r) * 72 + j + 32] = f2b(-x1 * cs.y + x2 * cs.x);
        }
      }
    }
    unsigned short* dp = dst + ((size_t)(bb * 16 + h) * 2048 + s_half) * 64;
#pragma unroll
    for (int i = 0; i < 8; ++i) {
      const int row = i * 8 + rlane;
      const bf16x8 v = *(const bf16x8*)&slab[row * 72 + clane * 8];
      *(bf16x8*)&dp[row * 64 + clane * 8] = v;
    }
  } else {
#pragma unroll
    for (int mi = 0; mi < 4; ++mi) {
      const int rl0 = mi * 16 + qrow;
#pragma unroll
      for (int ni = 0; ni < 4; ++ni) {
        const int d = ni * 16 + l15;
#pragma unroll
        for (int r = 0; r < 4; ++r)
          slab[d * 72 + rl0 + r] = f2b(acc[mi][ni][r]);
      }
    }
    unsigned short* vp = VTb + (size_t)(bb * 16 + h) * 64 * 2048 + s_half;
#pragma unroll
    for (int i = 0; i < 8; ++i) {
      const int d = i * 8 + rlane;
      const bf16x8 v = *(const bf16x8*)&slab[d * 72 + clane * 8];
      *(bf16x8*)&vp[(size_t)d * 2048 + clane * 8] = v;
    }
  }
}

// ------------------------------------------------------------------
// Flash attention v8 (causal). grid (32 bh, 8 p), 1024 threads = 16 waves.
// Waves (s=wid&3, qt=wid>>2): strip s of q-tiles jA=15-p then jB=p
// (sequential phases), keys split 4 ways by t64%4==qt -> 4 ACTIVE waves
// per SIMD every round. Rounds = 9 for every p (uniform blocks).
// 256-key staging per round (dbuf 2x64KB). 4-way flash merge via LDS.
// ------------------------------------------------------------------
DEVI void stage256(const unsigned short* __restrict__ Kh, const unsigned short* __restrict__ Vh,
                   int kbase, unsigned char* buf, int tid) {
#pragma unroll
  for (int i = 0; i < 4; ++i) {
    const int T = tid + i * 1024;           // wave-contiguous chunk index
    const int g = T >> 10;                  // 64-key group (wave-uniform)
    const int rem = T & 1023;               // isV wave-uniform (64-aligned)
    const int rr = (rem & 511) >> 3, c = rem & 7, cc = c ^ (rr & 7);
    unsigned char* dst = buf + (T & ~63) * 16;
    if (rem < 512)
      gload16(Kh + (size_t)(kbase + g * 64 + rr) * 64 + cc * 8, dst);
    else
      gload16(Vh + (size_t)rr * 2048 + kbase + g * 64 + cc * 8, dst);
  }
}

DEVI void attn_sub(const unsigned char* __restrict__ bufK, const unsigned char* __restrict__ bufV,
                   const bf16x8 qf[4], int s32, int kglob, bool diag, int qg, int ln, int hi,
                   float& m2, float& l_run, f32x16& acc0, f32x16& acc1) {
  const float C = 0.125f * 1.44269504f;       // scale * log2(e)
  const int rx = ln & 7;
  bf16x8 kf[4];
#pragma unroll
  for (int j = 0; j < 4; ++j) {
    const int cc = (2 * j + hi) ^ rx;
    kf[j] = *(const bf16x8*)(bufK + (s32 * 32 + ln) * 128 + cc * 16);
  }
  bf16x8 v0[2], v1[2];
#pragma unroll
  for (int p = 0; p < 2; ++p) {
    const int cc = (4 * s32 + 2 * p + hi) ^ rx;
    v0[p] = *(const bf16x8*)(bufV + ln * 128 + cc * 16);
    v1[p] = *(const bf16x8*)(bufV + (ln + 32) * 128 + cc * 16);
  }

  f32x16 stv = {};
  __builtin_amdgcn_s_setprio(1);
  stv = __builtin_amdgcn_mfma_f32_32x32x16_bf16(kf[0], qf[0], stv, 0, 0, 0);
  stv = __builtin_amdgcn_mfma_f32_32x32x16_bf16(kf[1], qf[1], stv, 0, 0, 0);
  stv = __builtin_amdgcn_mfma_f32_32x32x16_bf16(kf[2], qf[2], stv, 0, 0, 0);
  stv = __builtin_amdgcn_mfma_f32_32x32x16_bf16(kf[3], qf[3], stv, 0, 0, 0);
  __builtin_amdgcn_s_setprio(0);

  float sraw[16];
#pragma unroll
  for (int r = 0; r < 16; ++r) sraw[r] = stv[r];
  if (diag) {
#pragma unroll
    for (int r = 0; r < 16; ++r) {
      const int kg = kglob + (r & 3) + ((r >> 2) << 3) + (hi << 2);
      if (kg > qg) sraw[r] = -1e30f;
    }
  }
  float mraw = sraw[0];
#pragma unroll
  for (int r = 1; r < 16; ++r) mraw = fmaxf(mraw, sraw[r]);
  const float mlc = mraw * C;
  // defer-max: full cross-half max only when a rescale actually fires
  if (__any(mlc > m2 + 11.5416f)) {
    const float mnew = fmaxf(m2, halfmax(mlc));
    const float sc = exp2f(m2 - mnew);
    l_run *= sc;
#pragma unroll
    for (int r = 0; r < 16; ++r) { acc0[r] *= sc; acc1[r] *= sc; }
    m2 = mnew;
  }
  float p[16], ps = 0.f;
#pragma unroll
  for (int r = 0; r < 16; ++r) { p[r] = exp2f(fmaf(sraw[r], C, -m2)); ps += p[r]; }
  l_run += ps;                                // per-lane partial; halfsum later

  int cw[8];
#pragma unroll
  for (int i = 0; i < 8; ++i)
    asm("v_cvt_pk_bf16_f32 %0, %1, %2" : "=v"(cw[i]) : "v"(p[2 * i]), "v"(p[2 * i + 1]));
  int a0, a1, b0, b1, a2, a3, b2, b3;
  pl32swap(cw[0], cw[2], a0, b0);
  pl32swap(cw[1], cw[3], a1, b1);
  pl32swap(cw[4], cw[6], a2, b2);
  pl32swap(cw[5], cw[7], a3, b3);
  const bf16x8 pa0 = __builtin_bit_cast(bf16x8, (i32x4){a0, a1, b0, b1});
  const bf16x8 pa1 = __builtin_bit_cast(bf16x8, (i32x4){a2, a3, b2, b3});

  __builtin_amdgcn_s_setprio(1);
  acc0 = __builtin_amdgcn_mfma_f32_32x32x16_bf16(v0[0], pa0, acc0, 0, 0, 0);
  acc0 = __builtin_amdgcn_mfma_f32_32x32x16_bf16(v0[1], pa1, acc0, 0, 0, 0);
  acc1 = __builtin_amdgcn_mfma_f32_32x32x16_bf16(v1[0], pa0, acc1, 0, 0, 0);
  acc1 = __builtin_amdgcn_mfma_f32_32x32x16_bf16(v1[1], pa1, acc1, 0, 0, 0);
  __builtin_amdgcn_s_setprio(0);
}

DEVI void write_partial(float* M, int slot, const f32x16& a0, const f32x16& a1,
                        float m2, float l) {
#pragma unroll
  for (int r = 0; r < 16; ++r) { M[slot + r] = a0[r]; M[slot + 16 + r] = a1[r]; }
  M[slot + 32] = m2;
  M[slot + 33] = l;
}

DEVI void merge_state(const float* M, int slot, float& m, float& l,
                      f32x16& a0, f32x16& a1) {
  const float mp = M[slot + 32], lp = M[slot + 33];
  const float mn = fmaxf(m, mp);
  const float eo = exp2f(m - mn), ep = exp2f(mp - mn);
  l = l * eo + lp * ep;
#pragma unroll
  for (int r = 0; r < 16; ++r) {
    a0[r] = a0[r] * eo + M[slot + r] * ep;
    a1[r] = a1[r] * eo + M[slot + 16 + r] * ep;
  }
  m = mn;
}

DEVI void writeO(unsigned short* __restrict__ Ob, const f32x16& a0, const f32x16& a1,
                 float l, int bh, int q0, int ln, int hi) {
  const float il = 1.0f / l;
  const int b = bh >> 4, h = bh & 15;
  unsigned short* ob = Ob + ((size_t)(b * 2048 + q0 + ln)) * 1024 + h * 64;
#pragma unroll
  for (int g = 0; g < 4; ++g) {
    ushort4 o0, o1;
    o0.x = f2b(a0[4 * g + 0] * il); o0.y = f2b(a0[4 * g + 1] * il);
    o0.z = f2b(a0[4 * g + 2] * il); o0.w = f2b(a0[4 * g + 3] * il);
    o1.x = f2b(a1[4 * g + 0] * il); o1.y = f2b(a1[4 * g + 1] * il);
    o1.z = f2b(a1[4 * g + 2] * il); o1.w = f2b(a1[4 * g + 3] * il);
    *(ushort4*)&ob[8 * g + 4 * hi]      = o0;
    *(ushort4*)&ob[32 + 8 * g + 4 * hi] = o1;
  }
}

__global__ __launch_bounds__(1024, 4) void attn_kernel(
    const unsigned short* __restrict__ Qb, const unsigned short* __restrict__ Kb,
    const unsigned short* __restrict__ VTb, unsigned short* __restrict__ Ob) {
  __shared__ unsigned char smem[2][65536];    // dbuf of 256 keys: 4 x (K 8K | V 8K)
  const int tid = threadIdx.x;
  const int lane = tid & 63, wid = tid >> 6;
  const int ln = lane & 31, hi = lane >> 5;
  const int s = wid & 3, qt = wid >> 2;
  const int bh = blockIdx.x;
  const int p = blockIdx.y;
  const int jA = 15 - p, jB = p;
  const unsigned short* Qh = Qb + (size_t)bh * 2048 * 64;
  const unsigned short* Kh = Kb + (size_t)bh * 2048 * 64;
  const unsigned short* Vh = VTb + (size_t)bh * 64 * 2048;
  const int rA = (2 * jA + 5) >> 2;           // ceil((2jA+2)/4)
  const int rB = (2 * jB + 5) >> 2;           // rA + rB == 9 for all p

  auto load_q = [&](int q0, bf16x8 qf[4]) {
    const unsigned short* pq = Qh + (size_t)(q0 + ln) * 64 + hi * 8;
#pragma unroll
    for (int t = 0; t < 4; ++t) qf[t] = *(const bf16x8*)(pq + t * 16);
  };
  const int slot = (s * 64 + lane) * 34;
  int it = 0;

  // ================= phase A (q-tile jA) =================
  {
    f32x16 a0 = {}, a1 = {};
    float m2 = -1e30f, l = 0.f;
    bf16x8 qf[4];
    load_q(jA * 128 + s * 32, qf);
    const int q0 = jA * 128 + s * 32, qg = q0 + ln, top = q0 >> 5;

    stage256(Kh, Vh, 0, &smem[0][0], tid);
    __syncthreads();
    for (int kb = 0; kb < rA; ++kb, ++it) {
      stage256(Kh, Vh, (kb + 1 < rA) ? (kb + 1) * 256 : 0, &smem[(it + 1) & 1][0], tid);
      const unsigned char* bufK = &smem[it & 1][0] + qt * 16384;
      const unsigned char* bufV = bufK + 8192;
      const int t64 = 4 * kb + qt;
#pragma unroll
      for (int s32 = 0; s32 < 2; ++s32) {
        const int g32 = 2 * t64 + s32;
        if (g32 <= top)
          attn_sub(bufK, bufV, qf, s32, g32 * 32, g32 == top, qg, ln, hi, m2, l, a0, a1);
      }
      __syncthreads();
    }
    l = halfsum(l);

    float* R = (float*)&smem[(rA + 1) & 1][0];
    if (qt == 1) write_partial(R, slot, a0, a1, m2, l);
    __syncthreads();
    if (qt == 0) merge_state(R, slot, m2, l, a0, a1);
    __syncthreads();
    if (qt == 3) write_partial(R, slot, a0, a1, m2, l);
    __syncthreads();
    if (qt == 2) merge_state(R, slot, m2, l, a0, a1);
    __syncthreads();
    if (qt == 2) write_partial(R, slot, a0, a1, m2, l);
    __syncthreads();
    if (qt == 0) merge_state(R, slot, m2, l, a0, a1);
    __syncthreads();
    if (qt == 0) writeO(Ob, a0, a1, l, bh, q0, ln, hi);
  }

  // ================= phase B (q-tile jB) =================
  {
    f32x16 a0 = {}, a1 = {};
    float m2 = -1e30f, l = 0.f;
    bf16x8 qf[4];
    load_q(jB * 128 + s * 32, qf);
    const int q0 = jB * 128 + s * 32, qg = q0 + ln, top = q0 >> 5;

    for (int kb = 0; kb < rB; ++kb, ++it) {
      if (kb + 1 < rB) stage256(Kh, Vh, (kb + 1) * 256, &smem[(it + 1) & 1][0], tid);
      const unsigned char* bufK = &smem[it & 1][0] + qt * 16384;
      const unsigned char* bufV = bufK + 8192;
      const int t64 = 4 * kb + qt;
#pragma unroll
      for (int s32 = 0; s32 < 2; ++s32) {
        const int g32 = 2 * t64 + s32;
        if (g32 <= top)
          attn_sub(bufK, bufV, qf, s32, g32 * 32, g32 == top, qg, ln, hi, m2, l, a0, a1);
      }
      __syncthreads();
    }
    l = halfsum(l);

    float* R = (float*)&smem[0][0];
    if (qt == 1) write_partial(R, slot, a0, a1, m2, l);
    __syncthreads();
    if (qt == 0) merge_state(R, slot, m2, l, a0, a1);
    __syncthreads();
    if (qt == 3) write_partial(R, slot, a0, a1, m2, l);
    __syncthreads();
    if (qt == 2) merge_state(R, slot, m2, l, a0, a1);
    __syncthreads();
    if (qt == 2) write_partial(R, slot, a0, a1, m2, l);
    __syncthreads();
    if (qt == 0) {
      merge_state(R, slot, m2, l, a0, a1);
      writeO(Ob, a0, a1, l, bh, q0, ln, hi);
    }
  }
}

// ------------------------------------------------------------------
// GEMM2: out = Ob @ WoT^T, f32 epilogue. grid (8, 32)
// ------------------------------------------------------------------
__global__ __launch_bounds__(256) void gemm_out_kernel(
    const unsigned short* __restrict__ Ob, const unsigned short* __restrict__ WoT,
    float* __restrict__ out) {
  __shared__ unsigned short As[2][8192];
  __shared__ unsigned short Bs[2][8192];
  const int lane = threadIdx.x & 63, wid = threadIdx.x >> 6;
  const int m0 = blockIdx.y * 128, n0 = blockIdx.x * 128;
  const int wr = wid >> 1, wc = wid & 1;
  f32x4 acc[4][4] = {};
  gemm_mainloop(Ob, WoT, &As[0][0], &Bs[0][0], m0, n0, lane, wid, wr, wc, acc);
#pragma unroll
  for (int mi = 0; mi < 4; ++mi) {
    const int mrow = m0 + wr * 64 + mi * 16 + ((lane >> 4) << 2);
#pragma unroll
    for (int ni = 0; ni < 4; ++ni) {
      const int n = n0 + wc * 64 + ni * 16 + (lane & 15);
#pragma unroll
      for (int r = 0; r < 4; ++r)
        out[(size_t)(mrow + r) * 1024 + n] = acc[mi][ni][r];
    }
  }
}

// ------------------------------------------------------------------
extern "C" void kernel_launch(void* const* d_in, const int* in_sizes, int n_in,
                              void* d_out, int out_size, void* d_ws, size_t ws_size,
                              hipStream_t stream) {
  const float* x     = (const float*)d_in[0];
  const float* w_qkv = (const float*)d_in[1];
  const float* w_o   = (const float*)d_in[2];
  float* out = (float*)d_out;
  char* ws = (char*)d_ws;

  const size_t MB = 1 << 20;
  float2* cst = (float2*)(ws);                       // 512 KB
  unsigned short* Xb  = (unsigned short*)(ws + (512 << 10));            // 8 MB  (reused as Ob)
  unsigned short* WqT = (unsigned short*)(ws + (512 << 10) + 8  * MB);  // 6 MB
  unsigned short* WoT = (unsigned short*)(ws + (512 << 10) + 14 * MB);  // 2 MB
  unsigned short* Qb  = (unsigned short*)(ws + (512 << 10) + 16 * MB);  // 8 MB
  unsigned short* Kb  = (unsigned short*)(ws + (512 << 10) + 24 * MB);  // 8 MB
  unsigned short* VTb = (unsigned short*)(ws + (512 << 10) + 32 * MB);  // 8 MB
  unsigned short* Ob  = Xb;  // Xb dead after gemm1; total ws = 40.5 MB

  rope_table_kernel<<<dim3(256), dim3(256), 0, stream>>>(cst);
  cvt_x_kernel<<<dim3(4096), dim3(256), 0, stream>>>(x, Xb);
  transpose_kernel<<<dim3(96, 32), dim3(32, 8), 0, stream>>>(w_qkv, WqT, 1024, 3072);
  transpose_kernel<<<dim3(32, 32), dim3(32, 8), 0, stream>>>(w_o, WoT, 1024, 1024);
  gemm_qkv_kernel<<<dim3(24, 32), dim3(256), 0, stream>>>(Xb, WqT, cst, Qb, Kb, VTb);
  attn_kernel<<<dim3(32, 8), dim3(1024), 0, stream>>>(Qb, Kb, VTb, Ob);
  gemm_out_kernel<<<dim3(8, 32), dim3(256), 0, stream>>>(Ob, WoT, out);
}

// Round 12
// 119.322 us; speedup vs baseline: 1.0150x; 1.0150x over previous
//
#include <hip/hip_runtime.h>

typedef short bf16x8 __attribute__((ext_vector_type(8)));
typedef short bf16x4 __attribute__((ext_vector_type(4)));
typedef float f32x4 __attribute__((ext_vector_type(4)));
typedef float f32x16 __attribute__((ext_vector_type(16)));
typedef int i32x4 __attribute__((ext_vector_type(4)));

#define DEVI static __device__ __forceinline__

// f32 -> bf16 round-to-nearest-even
DEVI unsigned short f2b(float f) {
  unsigned u = __float_as_uint(f);
  u += 0x7FFFu + ((u >> 16) & 1u);
  return (unsigned short)(u >> 16);
}

DEVI void gload16(const void* g, void* l) {
  __builtin_amdgcn_global_load_lds((const __attribute__((address_space(1))) void*)g,
                                   (__attribute__((address_space(3))) void*)l, 16, 0, 0);
}

// permlane32_swap: outa = {a.row0, b.row0}, outb = {a.row1, b.row1}
DEVI void pl32swap(int a, int b, int& outa, int& outb) {
#if __has_builtin(__builtin_amdgcn_permlane32_swap)
  auto r = __builtin_amdgcn_permlane32_swap(a, b, false, false);
  outa = ((const int*)&r)[0];
  outb = ((const int*)&r)[1];
#else
  int bp = __shfl_xor(b, 32);
  int ap = __shfl_xor(a, 32);
  outa = (threadIdx.x & 32) ? bp : a;
  outb = (threadIdx.x & 32) ? b : ap;
#endif
}

DEVI float halfmax(float x) {
  int o0, o1;
  pl32swap(__float_as_int(x), __float_as_int(x), o0, o1);
  return fmaxf(__int_as_float(o0), __int_as_float(o1));
}
DEVI float halfsum(float x) {
  int o0, o1;
  pl32swap(__float_as_int(x), __float_as_int(x), o0, o1);
  return __int_as_float(o0) + __int_as_float(o1);
}

// ------------------------------------------------------------------
// RoPE table: cst[s][j] = (cos, sin) packed float2, s<2048, j<32
// ------------------------------------------------------------------
__global__ void rope_table_kernel(float2* __restrict__ cst) {
  int i = blockIdx.x * 256 + threadIdx.x;     // 65536 total
  int s = i >> 5, j = i & 31;
  float inv = powf(10000.0f, -(float)j * (1.0f / 32.0f));
  float a = (float)s * inv;
  cst[i] = make_float2(cosf(a), sinf(a));
}

// ------------------------------------------------------------------
// x f32 -> bf16 (vectorized)
// ------------------------------------------------------------------
__global__ void cvt_x_kernel(const float* __restrict__ x, unsigned short* __restrict__ xb) {
  int i = blockIdx.x * 256 + threadIdx.x;     // n/4 threads
  float4 v = ((const float4*)x)[i];
  ushort4 o;
  o.x = f2b(v.x); o.y = f2b(v.y); o.z = f2b(v.z); o.w = f2b(v.w);
  ((ushort4*)xb)[i] = o;
}

// ------------------------------------------------------------------
// Fused transpose of both weights: W [K][N] f32 -> WT [N][K] bf16
// bx < 96: w_qkv (N=3072); else w_o (N=1024). grid (128, 32), block (32,8)
// ------------------------------------------------------------------
__global__ void transpose2_kernel(const float* __restrict__ W1, unsigned short* __restrict__ WT1,
                                  const float* __restrict__ W2, unsigned short* __restrict__ WT2) {
  __shared__ float tile[32][33];
  int bx = blockIdx.x;
  const float* W; unsigned short* WT; int N;
  if (bx < 96) { W = W1; WT = WT1; N = 3072; }
  else         { W = W2; WT = WT2; N = 1024; bx -= 96; }
  const int K = 1024;
  int n0 = bx * 32, k0 = blockIdx.y * 32;
  int tx = threadIdx.x, ty = threadIdx.y;     // 32 x 8
#pragma unroll
  for (int i = 0; i < 32; i += 8)
    tile[ty + i][tx] = W[(size_t)(k0 + ty + i) * N + n0 + tx];
  __syncthreads();
#pragma unroll
  for (int i = 0; i < 32; i += 8)
    WT[(size_t)(n0 + ty + i) * K + k0 + tx] = f2b(tile[tx][ty + i]);
}

// ------------------------------------------------------------------
// Shared GEMM mainloop: 128x128 tile, 4 waves (2x2), rolling counted-vmcnt
// pipeline.
// ------------------------------------------------------------------
DEVI void gemm_mainloop(const unsigned short* __restrict__ A, const unsigned short* __restrict__ B,
                        unsigned short* As, unsigned short* Bs,   // each [2][8192]
                        int m0, int n0, int lane, int wid, int wr, int wc,
                        f32x4 acc[4][4]) {
  const int srow = lane >> 3;
  const int scc = ((lane & 7) ^ srow) * 8;
  const int rx = lane & 7;
  auto stage = [&](int k0, int nb) {
    unsigned short* Ad = As + nb * 8192;
    unsigned short* Bd = Bs + nb * 8192;
#pragma unroll
    for (int i = 0; i < 4; ++i) {
      const int c = i * 4 + wid;
      const int row = c * 8 + srow;
      gload16(A + (size_t)(m0 + row) * 1024 + k0 + scc, (char*)Ad + c * 1024);
      gload16(B + (size_t)(n0 + row) * 1024 + k0 + scc, (char*)Bd + c * 1024);
    }
  };
  auto compute = [&](int nb) {
    const unsigned short* Ab = As + nb * 8192;
    const unsigned short* Bb = Bs + nb * 8192;
#pragma unroll
    for (int kk = 0; kk < 64; kk += 32) {
      const int cc = (((kk >> 3) + (lane >> 4)) ^ rx) * 8;
      bf16x8 a[4], b[4];
#pragma unroll
      for (int mi = 0; mi < 4; ++mi)
        a[mi] = *(const bf16x8*)&Ab[(wr * 64 + mi * 16 + (lane & 15)) * 64 + cc];
#pragma unroll
      for (int ni = 0; ni < 4; ++ni)
        b[ni] = *(const bf16x8*)&Bb[(wc * 64 + ni * 16 + (lane & 15)) * 64 + cc];
      __builtin_amdgcn_s_setprio(1);
#pragma unroll
      for (int mi = 0; mi < 4; ++mi)
#pragma unroll
        for (int ni = 0; ni < 4; ++ni)
          acc[mi][ni] = __builtin_amdgcn_mfma_f32_16x16x32_bf16(a[mi], b[ni], acc[mi][ni], 0, 0, 0);
      __builtin_amdgcn_s_setprio(0);
    }
  };
  stage(0, 0);
  stage(64, 1);
  for (int t = 0; t < 15; ++t) {
    asm volatile("s_waitcnt vmcnt(8)" ::: "memory");
    __builtin_amdgcn_s_barrier();
    compute(t & 1);
    __builtin_amdgcn_s_barrier();
    if (t < 14) stage((t + 2) * 64, t & 1);
  }
  asm volatile("s_waitcnt vmcnt(0)" ::: "memory");
  __builtin_amdgcn_s_barrier();
  compute(1);
}

// ------------------------------------------------------------------
// GEMM1 v6 (unchanged from R11): 128x128 rolling mainloop + coalesced
// LDS-slab RoPE epilogue. grid (24,32), 64KB LDS, 2 blocks/CU.
// ------------------------------------------------------------------
__global__ __launch_bounds__(256, 2) void gemm_qkv_kernel(
    const unsigned short* __restrict__ Xb, const unsigned short* __restrict__ WT,
    const float2* __restrict__ cst,
    unsigned short* __restrict__ Qb, unsigned short* __restrict__ Kb,
    unsigned short* __restrict__ VTb) {
  __shared__ unsigned short As[2][8192];      // 32 KB
  __shared__ unsigned short Bs[2][8192];      // 32 KB
  const int lane = threadIdx.x & 63, wid = threadIdx.x >> 6;
  const int flat = blockIdx.y * 24 + blockIdx.x;
  const int nf = (flat & 7) * 96 + (flat >> 3);
  const int bx = nf % 24, by = nf / 24;
  const int m0 = by * 128, n0 = bx * 128;
  const int wr = wid >> 1, wc = wid & 1;
  f32x4 acc[4][4] = {};
  gemm_mainloop(Xb, WT, &As[0][0], &Bs[0][0], m0, n0, lane, wid, wr, wc, acc);

  // ---- coalesced epilogue via wave-private LDS slab (64x72 ushort) ----
  __syncthreads();                            // all waves done with As/Bs
  unsigned short* slab = (unsigned short*)((char*)&As[0][0] + wid * 9216);
  const int n_base = n0 + wc * 64;            // one head chunk per wave
  const int ty = n_base >> 10;                // 0=q 1=k 2=v
  const int h = (n_base & 1023) >> 6;
  const int qrow = (lane >> 4) << 2;
  const int l15 = lane & 15;
  const int rlane = lane >> 3, clane = lane & 7;
  const int rowg = m0 + wr * 64;
  const int s_half = rowg & 2047, bb = rowg >> 11;

  if (ty < 2) {
    unsigned short* dst = (ty == 0) ? Qb : Kb;
#pragma unroll
    for (int mi = 0; mi < 4; ++mi) {
      const int rl0 = mi * 16 + qrow;
#pragma unroll
      for (int r = 0; r < 4; ++r) {
#pragma unroll
        for (int ni = 0; ni < 2; ++ni) {
          const int j = ni * 16 + l15;
          const float2 cs = cst[(s_half + rl0 + r) * 32 + j];
          const float x1 = acc[mi][ni][r], x2 = acc[mi][ni + 2][r];
          slab[(rl0 + r) * 72 + j]      = f2b(x1 * cs.x + x2 * cs.y);
          slab[(rl0 + r) * 72 + j + 32] = f2b(-x1 * cs.y + x2 * cs.x);
        }
      }
    }
    unsigned short* dp = dst + ((size_t)(bb * 16 + h) * 2048 + s_half) * 64;
#pragma unroll
    for (int i = 0; i < 8; ++i) {
      const int row = i * 8 + rlane;
      const bf16x8 v = *(const bf16x8*)&slab[row * 72 + clane * 8];
      *(bf16x8*)&dp[row * 64 + clane * 8] = v;
    }
  } else {
#pragma unroll
    for (int mi = 0; mi < 4; ++mi) {
      const int rl0 = mi * 16 + qrow;
#pragma unroll
      for (int ni = 0; ni < 4; ++ni) {
        const int d = ni * 16 + l15;
#pragma unroll
        for (int r = 0; r < 4; ++r)
          slab[d * 72 + rl0 + r] = f2b(acc[mi][ni][r]);
      }
    }
    unsigned short* vp = VTb + (size_t)(bb * 16 + h) * 64 * 2048 + s_half;
#pragma unroll
    for (int i = 0; i < 8; ++i) {
      const int d = i * 8 + rlane;
      const bf16x8 v = *(const bf16x8*)&slab[d * 72 + clane * 8];
      *(bf16x8*)&vp[(size_t)d * 2048 + clane * 8] = v;
    }
  }
}

// ------------------------------------------------------------------
// Flash attention v9 (causal). grid (32 bh, 8 p), 512 threads (8 waves),
// key-split halves (v6 skeleton) BUT each 64-key tile processed in ONE
// fused call: two independent QK^T chains, joint max / single defer-max
// check per 64 keys, exp2 in place on MFMA results, V frags loaded between
// QK and softmax. launch_bounds(512,2) -> 256-reg cap (no tight-budget
// register shuffling). Merge + epilogue = v7 structure.
// ------------------------------------------------------------------
DEVI void stage128(const unsigned short* __restrict__ Kh, const unsigned short* __restrict__ Vh,
                   int kbase, unsigned char* buf, int tid) {
  const int r = tid >> 3, c = tid & 7, cc = c ^ (r & 7);
  const int dst = (tid & ~63) * 16;
#pragma unroll
  for (int q = 0; q < 2; ++q) {
    unsigned char* b = buf + q * 16384;
    gload16(Kh + (size_t)(kbase + q * 64 + r) * 64 + cc * 8, b + dst);
    gload16(Vh + (size_t)r * 2048 + kbase + q * 64 + cc * 8, b + 8192 + dst);
  }
}

DEVI void build_pa(const f32x16& s, bf16x8& pa0, bf16x8& pa1) {
  int cw[8];
#pragma unroll
  for (int i = 0; i < 8; ++i)
    asm("v_cvt_pk_bf16_f32 %0, %1, %2" : "=v"(cw[i]) : "v"(s[2 * i]), "v"(s[2 * i + 1]));
  int a0, a1, b0, b1, a2, a3, b2, b3;
  pl32swap(cw[0], cw[2], a0, b0);
  pl32swap(cw[1], cw[3], a1, b1);
  pl32swap(cw[4], cw[6], a2, b2);
  pl32swap(cw[5], cw[7], a3, b3);
  pa0 = __builtin_bit_cast(bf16x8, (i32x4){a0, a1, b0, b1});
  pa1 = __builtin_bit_cast(bf16x8, (i32x4){a2, a3, b2, b3});
}

// Full 64-key tile (2 subtiles), subtile1 optionally masked (diag1).
DEVI void attn_pair(const unsigned char* __restrict__ bufK, const unsigned char* __restrict__ bufV,
                    const bf16x8 qf[4], int kglob, bool diag1, int qg, int ln, int hi,
                    float& m2, float& l_run, f32x16& acc0, f32x16& acc1) {
  const float C = 0.125f * 1.44269504f;       // scale * log2(e)
  const int rx = ln & 7;
  f32x16 s0 = {}, s1 = {};
  {
    bf16x8 k0[4], k1[4];
#pragma unroll
    for (int j = 0; j < 4; ++j) {
      const int cc = (2 * j + hi) ^ rx;
      k0[j] = *(const bf16x8*)(bufK + ln * 128 + cc * 16);
      k1[j] = *(const bf16x8*)(bufK + (32 + ln) * 128 + cc * 16);
    }
    __builtin_amdgcn_s_setprio(1);
#pragma unroll
    for (int j = 0; j < 4; ++j) {             // two independent chains
      s0 = __builtin_amdgcn_mfma_f32_32x32x16_bf16(k0[j], qf[j], s0, 0, 0, 0);
      s1 = __builtin_amdgcn_mfma_f32_32x32x16_bf16(k1[j], qf[j], s1, 0, 0, 0);
    }
    __builtin_amdgcn_s_setprio(0);
  }
  // V frags for both subtiles (issue early; consumed after softmax)
  bf16x8 va[2][2], vb[2][2];                  // [subtile][k-slice]; va: d<32, vb: d>=32
#pragma unroll
  for (int st = 0; st < 2; ++st)
#pragma unroll
    for (int p = 0; p < 2; ++p) {
      const int cc = (4 * st + 2 * p + hi) ^ rx;
      va[st][p] = *(const bf16x8*)(bufV + ln * 128 + cc * 16);
      vb[st][p] = *(const bf16x8*)(bufV + (ln + 32) * 128 + cc * 16);
    }

  if (diag1) {
#pragma unroll
    for (int r = 0; r < 16; ++r) {
      const int kg = kglob + 32 + (r & 3) + ((r >> 2) << 3) + (hi << 2);
      if (kg > qg) s1[r] = -1e30f;
    }
  }
  // joint max over all 64 keys (one tree, one defer-max check)
  float mraw = fmaxf(s0[0], s1[0]);
#pragma unroll
  for (int r = 1; r < 16; ++r) mraw = fmaxf(mraw, fmaxf(s0[r], s1[r]));
  const float mlc = mraw * C;
  if (__any(mlc > m2 + 11.5416f)) {
    const float mnew = fmaxf(m2, halfmax(mlc));
    const float sc = exp2f(m2 - mnew);
    l_run *= sc;
#pragma unroll
    for (int r = 0; r < 16; ++r) { acc0[r] *= sc; acc1[r] *= sc; }
    m2 = mnew;
  }
  float ps0 = 0.f, ps1 = 0.f;
#pragma unroll
  for (int r = 0; r < 16; ++r) { s0[r] = exp2f(fmaf(s0[r], C, -m2)); ps0 += s0[r]; }
#pragma unroll
  for (int r = 0; r < 16; ++r) { s1[r] = exp2f(fmaf(s1[r], C, -m2)); ps1 += s1[r]; }
  l_run += ps0 + ps1;                         // per-lane partial; halfsum at end

  bf16x8 pa[2][2];
  build_pa(s0, pa[0][0], pa[0][1]);
  build_pa(s1, pa[1][0], pa[1][1]);

  __builtin_amdgcn_s_setprio(1);
#pragma unroll
  for (int st = 0; st < 2; ++st) {
    acc0 = __builtin_amdgcn_mfma_f32_32x32x16_bf16(va[st][0], pa[st][0], acc0, 0, 0, 0);
    acc1 = __builtin_amdgcn_mfma_f32_32x32x16_bf16(vb[st][0], pa[st][0], acc1, 0, 0, 0);
    acc0 = __builtin_amdgcn_mfma_f32_32x32x16_bf16(va[st][1], pa[st][1], acc0, 0, 0, 0);
    acc1 = __builtin_amdgcn_mfma_f32_32x32x16_bf16(vb[st][1], pa[st][1], acc1, 0, 0, 0);
  }
  __builtin_amdgcn_s_setprio(0);
}

// Single subtile (always the diagonal one): keys kglob..kglob+31.
DEVI void attn_single(const unsigned char* __restrict__ bufK, const unsigned char* __restrict__ bufV,
                      const bf16x8 qf[4], int kglob, int qg, int ln, int hi,
                      float& m2, float& l_run, f32x16& acc0, f32x16& acc1) {
  const float C = 0.125f * 1.44269504f;
  const int rx = ln & 7;
  f32x16 s0 = {};
  {
    bf16x8 k0[4];
#pragma unroll
    for (int j = 0; j < 4; ++j) {
      const int cc = (2 * j + hi) ^ rx;
      k0[j] = *(const bf16x8*)(bufK + ln * 128 + cc * 16);
    }
    __builtin_amdgcn_s_setprio(1);
#pragma unroll
    for (int j = 0; j < 4; ++j)
      s0 = __builtin_amdgcn_mfma_f32_32x32x16_bf16(k0[j], qf[j], s0, 0, 0, 0);
    __builtin_amdgcn_s_setprio(0);
  }
  bf16x8 va[2], vb[2];
#pragma unroll
  for (int p = 0; p < 2; ++p) {
    const int cc = (2 * p + hi) ^ rx;
    va[p] = *(const bf16x8*)(bufV + ln * 128 + cc * 16);
    vb[p] = *(const bf16x8*)(bufV + (ln + 32) * 128 + cc * 16);
  }
#pragma unroll
  for (int r = 0; r < 16; ++r) {
    const int kg = kglob + (r & 3) + ((r >> 2) << 3) + (hi << 2);
    if (kg > qg) s0[r] = -1e30f;
  }
  float mraw = s0[0];
#pragma unroll
  for (int r = 1; r < 16; ++r) mraw = fmaxf(mraw, s0[r]);
  const float mlc = mraw * C;
  if (__any(mlc > m2 + 11.5416f)) {
    const float mnew = fmaxf(m2, halfmax(mlc));
    const float sc = exp2f(m2 - mnew);
    l_run *= sc;
#pragma unroll
    for (int r = 0; r < 16; ++r) { acc0[r] *= sc; acc1[r] *= sc; }
    m2 = mnew;
  }
  float ps = 0.f;
#pragma unroll
  for (int r = 0; r < 16; ++r) { s0[r] = exp2f(fmaf(s0[r], C, -m2)); ps += s0[r]; }
  l_run += ps;

  bf16x8 pa0, pa1;
  build_pa(s0, pa0, pa1);
  __builtin_amdgcn_s_setprio(1);
  acc0 = __builtin_amdgcn_mfma_f32_32x32x16_bf16(va[0], pa0, acc0, 0, 0, 0);
  acc1 = __builtin_amdgcn_mfma_f32_32x32x16_bf16(vb[0], pa0, acc1, 0, 0, 0);
  acc0 = __builtin_amdgcn_mfma_f32_32x32x16_bf16(va[1], pa1, acc0, 0, 0, 0);
  acc1 = __builtin_amdgcn_mfma_f32_32x32x16_bf16(vb[1], pa1, acc1, 0, 0, 0);
  __builtin_amdgcn_s_setprio(0);
}

DEVI void write_partial(float* M, int slot, const f32x16& a0, const f32x16& a1,
                        float m2, float l) {
#pragma unroll
  for (int r = 0; r < 16; ++r) { M[slot + r] = a0[r]; M[slot + 16 + r] = a1[r]; }
  M[slot + 32] = m2;
  M[slot + 33] = l;
}

DEVI void write_merged(unsigned short* __restrict__ Ob, const float* M, int slot,
                       const f32x16& acc0, const f32x16& acc1, float m2, float l_run,
                       int bh, int q0, int ln, int hi) {
  const float mp = M[slot + 32], lp = M[slot + 33];
  const float m = fmaxf(m2, mp);
  const float eo = exp2f(m2 - m), ep = exp2f(mp - m);
  const float il = 1.0f / (l_run * eo + lp * ep);
  const int b = bh >> 4, h = bh & 15;
  unsigned short* ob = Ob + ((size_t)(b * 2048 + q0 + ln)) * 1024 + h * 64;
#pragma unroll
  for (int g = 0; g < 4; ++g) {
    ushort4 o0, o1;
    o0.x = f2b((acc0[4 * g + 0] * eo + M[slot + 4 * g + 0] * ep) * il);
    o0.y = f2b((acc0[4 * g + 1] * eo + M[slot + 4 * g + 1] * ep) * il);
    o0.z = f2b((acc0[4 * g + 2] * eo + M[slot + 4 * g + 2] * ep) * il);
    o0.w = f2b((acc0[4 * g + 3] * eo + M[slot + 4 * g + 3] * ep) * il);
    o1.x = f2b((acc1[4 * g + 0] * eo + M[slot + 16 + 4 * g + 0] * ep) * il);
    o1.y = f2b((acc1[4 * g + 1] * eo + M[slot + 16 + 4 * g + 1] * ep) * il);
    o1.z = f2b((acc1[4 * g + 2] * eo + M[slot + 16 + 4 * g + 2] * ep) * il);
    o1.w = f2b((acc1[4 * g + 3] * eo + M[slot + 16 + 4 * g + 3] * ep) * il);
    *(ushort4*)&ob[8 * g + 4 * hi]      = o0;
    *(ushort4*)&ob[32 + 8 * g + 4 * hi] = o1;
  }
}

__global__ __launch_bounds__(512, 2) void attn_kernel(
    const unsigned short* __restrict__ Qb, const unsigned short* __restrict__ Kb,
    const unsigned short* __restrict__ VTb, unsigned short* __restrict__ Ob) {
  __shared__ unsigned char smem[2][2][16384];   // [dbuf][half][K 8K | V 8K]
  const int tid = threadIdx.x;
  const int lane = tid & 63, wid = tid >> 6;
  const int ln = lane & 31, hi = lane >> 5;
  const int s = wid & 3, half = wid >> 2;
  const int bh = blockIdx.x;
  const int p = blockIdx.y;
  const int jA = 15 - p, jB = p;
  const unsigned short* Qh = Qb + (size_t)bh * 2048 * 64;
  const unsigned short* Kh = Kb + (size_t)bh * 2048 * 64;
  const unsigned short* Vh = VTb + (size_t)bh * 64 * 2048;

  f32x16 aA0 = {}, aA1 = {}, aB0 = {}, aB1 = {};
  float mA = -1e30f, lA = 0.f, mB = -1e30f, lB = 0.f;
  int it = 0;

  auto load_q = [&](int q0, bf16x8 qf[4]) {
    const unsigned short* pq = Qh + (size_t)(q0 + ln) * 64 + hi * 8;
#pragma unroll
    for (int t = 0; t < 4; ++t) qf[t] = *(const bf16x8*)(pq + t * 16);
  };
  auto run_phase = [&](int j, const bf16x8 qf[4], f32x16& acc0, f32x16& acc1,
                       float& m2, float& l_run, int q0, int nextFirst) {
    const int qg = q0 + ln;
    const int top = q0 >> 5;
    for (int kb = 0; kb <= j; ++kb, ++it) {
      const int nxt = (kb < j) ? (kb + 1) * 128 : nextFirst;
      if (nxt >= 0) stage128(Kh, Vh, nxt, &smem[(it + 1) & 1][0][0], tid);
      const unsigned char* bufK = &smem[it & 1][half][0];
      const unsigned char* bufV = bufK + 8192;
      const int t64 = 2 * kb + half;
      const int nv = top - 2 * t64 + 1;       // valid subtiles in this 64-key tile
      if (nv >= 2)
        attn_pair(bufK, bufV, qf, t64 * 64, top == 2 * t64 + 1, qg, ln, hi,
                  m2, l_run, acc0, acc1);
      else if (nv == 1)                       // single valid == diagonal subtile
        attn_single(bufK, bufV, qf, t64 * 64, qg, ln, hi, m2, l_run, acc0, acc1);
      __syncthreads();
    }
  };

  bf16x8 qfA[4];
  load_q(jA * 128 + s * 32, qfA);
  stage128(Kh, Vh, 0, &smem[0][0][0], tid);
  __syncthreads();
  run_phase(jA, qfA, aA0, aA1, mA, lA, jA * 128 + s * 32, /*nextFirst=*/0);
  bf16x8 qfB[4];
  load_q(jB * 128 + s * 32, qfB);
  run_phase(jB, qfB, aB0, aB1, mB, lB, jB * 128 + s * 32, /*nextFirst=*/-1);

  // totals: l kept per-lane in the loop, one halfsum here
  lA = halfsum(lA);
  lB = halfsum(lB);

  // ---- split-K merge between halves (flash combine), then final O writes ----
  float* M = (float*)&smem[0][0][0];
  const int slot = (s * 64 + lane) * 34;
  if (half == 1) write_partial(M, slot, aA0, aA1, mA, lA);
  __syncthreads();
  if (half == 0) write_merged(Ob, M, slot, aA0, aA1, mA, lA, bh, jA * 128 + s * 32, ln, hi);
  __syncthreads();
  if (half == 0) write_partial(M, slot, aB0, aB1, mB, lB);
  __syncthreads();
  if (half == 1) write_merged(Ob, M, slot, aB0, aB1, mB, lB, bh, jB * 128 + s * 32, ln, hi);
}

// ------------------------------------------------------------------
// GEMM2: out = Ob @ WoT^T, f32 epilogue. grid (8, 32)
// ------------------------------------------------------------------
__global__ __launch_bounds__(256) void gemm_out_kernel(
    const unsigned short* __restrict__ Ob, const unsigned short* __restrict__ WoT,
    float* __restrict__ out) {
  __shared__ unsigned short As[2][8192];
  __shared__ unsigned short Bs[2][8192];
  const int lane = threadIdx.x & 63, wid = threadIdx.x >> 6;
  const int m0 = blockIdx.y * 128, n0 = blockIdx.x * 128;
  const int wr = wid >> 1, wc = wid & 1;
  f32x4 acc[4][4] = {};
  gemm_mainloop(Ob, WoT, &As[0][0], &Bs[0][0], m0, n0, lane, wid, wr, wc, acc);
#pragma unroll
  for (int mi = 0; mi < 4; ++mi) {
    const int mrow = m0 + wr * 64 + mi * 16 + ((lane >> 4) << 2);
#pragma unroll
    for (int ni = 0; ni < 4; ++ni) {
      const int n = n0 + wc * 64 + ni * 16 + (lane & 15);
#pragma unroll
      for (int r = 0; r < 4; ++r)
        out[(size_t)(mrow + r) * 1024 + n] = acc[mi][ni][r];
    }
  }
}

// ------------------------------------------------------------------
extern "C" void kernel_launch(void* const* d_in, const int* in_sizes, int n_in,
                              void* d_out, int out_size, void* d_ws, size_t ws_size,
                              hipStream_t stream) {
  const float* x     = (const float*)d_in[0];
  const float* w_qkv = (const float*)d_in[1];
  const float* w_o   = (const float*)d_in[2];
  float* out = (float*)d_out;
  char* ws = (char*)d_ws;

  const size_t MB = 1 << 20;
  float2* cst = (float2*)(ws);                       // 512 KB
  unsigned short* Xb  = (unsigned short*)(ws + (512 << 10));            // 8 MB  (reused as Ob)
  unsigned short* WqT = (unsigned short*)(ws + (512 << 10) + 8  * MB);  // 6 MB
  unsigned short* WoT = (unsigned short*)(ws + (512 << 10) + 14 * MB);  // 2 MB
  unsigned short* Qb  = (unsigned short*)(ws + (512 << 10) + 16 * MB);  // 8 MB
  unsigned short* Kb  = (unsigned short*)(ws + (512 << 10) + 24 * MB);  // 8 MB
  unsigned short* VTb = (unsigned short*)(ws + (512 << 10) + 32 * MB);  // 8 MB
  unsigned short* Ob  = Xb;  // Xb dead after gemm1; total ws = 40.5 MB

  rope_table_kernel<<<dim3(256), dim3(256), 0, stream>>>(cst);
  cvt_x_kernel<<<dim3(4096), dim3(256), 0, stream>>>(x, Xb);
  transpose2_kernel<<<dim3(128, 32), dim3(32, 8), 0, stream>>>(w_qkv, WqT, w_o, WoT);
  gemm_qkv_kernel<<<dim3(24, 32), dim3(256), 0, stream>>>(Xb, WqT, cst, Qb, Kb, VTb);
  attn_kernel<<<dim3(32, 8), dim3(512), 0, stream>>>(Qb, Kb, VTb, Ob);
  gemm_out_kernel<<<dim3(8, 32), dim3(256), 0, stream>>>(Ob, WoT, out);
}